// Round 1
// baseline (675.378 us; speedup 1.0000x reference)
//
#include <hip/hip_runtime.h>
#include <math.h>

// Problem constants (fixed by reference): IN=512, H=4, C=32, H*C=128.
constexpr int IN_F = 512;
constexpr int NH   = 4;
constexpr int CH   = 32;
constexpr int HC   = 128;   // NH*CH

// ---------------------------------------------------------------------------
// Init: out[n,j] = bias[j]  (aggregation atomically adds on top); denom = 0.
// ---------------------------------------------------------------------------
__global__ void init_out_denom(float* __restrict__ out,
                               const float* __restrict__ bias,
                               float* __restrict__ denom, int N) {
    int i = blockIdx.x * blockDim.x + threadIdx.x;
    int total = N * HC;
    if (i < total) out[i] = bias[i & (HC - 1)];
    if (i < N * NH) denom[i] = 0.0f;
}

// ---------------------------------------------------------------------------
// GEMM: ht[M x 128] = h[M x 512] * W[512 x 128], fp32, LDS-tiled.
// BM=64, BN=128, BK=32, 256 threads, each computes 4x8 outputs.
// ---------------------------------------------------------------------------
__global__ __launch_bounds__(256) void gemm_ht(const float* __restrict__ A,
                                               const float* __restrict__ B,
                                               float* __restrict__ C, int M) {
    constexpr int BM = 64, BK = 32;
    __shared__ float As[BK][BM + 1];   // [k][m], +1 pad: conflict-free writes
    __shared__ float Bs[BK][HC];       // [k][n]

    const int tid  = threadIdx.x;
    const int brow = blockIdx.x * BM;
    const int ty = tid >> 4;        // 0..15
    const int tx = tid & 15;        // 0..15
    const int m0 = ty * 4;
    const int n0 = tx * 8;

    // A-load mapping: 4 threads per row, 8 floats each
    const int ar = tid >> 2;          // 0..63
    const int ac = (tid & 3) * 8;     // 0,8,16,24
    // B-load mapping: 8 rows per pass, 4 passes
    const int br = tid >> 5;          // 0..7
    const int bc = (tid & 31) * 4;

    float acc[4][8] = {};

    for (int k0 = 0; k0 < IN_F; k0 += BK) {
        const int grow = brow + ar;
        float4 a0, a1;
        if (grow < M) {
            const float* ap = A + (size_t)grow * IN_F + k0 + ac;
            a0 = *(const float4*)(ap);
            a1 = *(const float4*)(ap + 4);
        } else {
            a0 = make_float4(0.f, 0.f, 0.f, 0.f);
            a1 = a0;
        }
        float4 bq[4];
#pragma unroll
        for (int p = 0; p < 4; ++p)
            bq[p] = *(const float4*)(B + (size_t)(k0 + br + p * 8) * HC + bc);

        __syncthreads();
        As[ac + 0][ar] = a0.x;  As[ac + 1][ar] = a0.y;
        As[ac + 2][ar] = a0.z;  As[ac + 3][ar] = a0.w;
        As[ac + 4][ar] = a1.x;  As[ac + 5][ar] = a1.y;
        As[ac + 6][ar] = a1.z;  As[ac + 7][ar] = a1.w;
#pragma unroll
        for (int p = 0; p < 4; ++p)
            *(float4*)&Bs[br + p * 8][bc] = bq[p];
        __syncthreads();

#pragma unroll
        for (int kk = 0; kk < BK; ++kk) {
            float av[4], bv[8];
#pragma unroll
            for (int i = 0; i < 4; ++i) av[i] = As[kk][m0 + i];
            float4 b0 = *(const float4*)&Bs[kk][n0];
            float4 b1 = *(const float4*)&Bs[kk][n0 + 4];
            bv[0] = b0.x; bv[1] = b0.y; bv[2] = b0.z; bv[3] = b0.w;
            bv[4] = b1.x; bv[5] = b1.y; bv[6] = b1.z; bv[7] = b1.w;
#pragma unroll
            for (int i = 0; i < 4; ++i)
#pragma unroll
                for (int j = 0; j < 8; ++j)
                    acc[i][j] += av[i] * bv[j];
        }
    }

#pragma unroll
    for (int i = 0; i < 4; ++i) {
        const int row = brow + m0 + i;
        if (row < M) {
            float4 c0 = make_float4(acc[i][0], acc[i][1], acc[i][2], acc[i][3]);
            float4 c1 = make_float4(acc[i][4], acc[i][5], acc[i][6], acc[i][7]);
            *(float4*)(C + (size_t)row * HC + n0)     = c0;
            *(float4*)(C + (size_t)row * HC + n0 + 4) = c1;
        }
    }
}

// ---------------------------------------------------------------------------
// Per-(node,head) attention logits: a_s[n,h] = <ht[n,h,:], att_src[h,:]>
// ---------------------------------------------------------------------------
__global__ void node_logits(const float* __restrict__ ht,
                            const float* __restrict__ att_src,
                            const float* __restrict__ att_dst,
                            float* __restrict__ a_s, float* __restrict__ a_d,
                            int N) {
    int t = blockIdx.x * blockDim.x + threadIdx.x;   // t = n*NH + h
    if (t >= N * NH) return;
    const int n  = t >> 2;
    const int hh = t & 3;
    const float* p  = ht + (size_t)n * HC + hh * CH;
    const float* ps = att_src + hh * CH;
    const float* pd = att_dst + hh * CH;
    float s = 0.f, d = 0.f;
#pragma unroll
    for (int c = 0; c < CH; c += 4) {
        float4 v  = *(const float4*)(p + c);
        float4 as = *(const float4*)(ps + c);
        float4 ad = *(const float4*)(pd + c);
        s += v.x * as.x + v.y * as.y + v.z * as.z + v.w * as.w;
        d += v.x * ad.x + v.y * ad.y + v.z * ad.z + v.w * ad.w;
    }
    a_s[t] = s;
    a_d[t] = d;
}

__device__ __forceinline__ float edge_ex(float as, float ad) {
    // exp(sigmoid(as + ad))
    float x = as + ad;
    float sg = 1.0f / (1.0f + __expf(-x));
    return __expf(sg);
}

// ---------------------------------------------------------------------------
// Edge pass 1: denom[dst,h] += exp(sigmoid(a_s[src,h] + a_d[dst,h]))
// One thread per edge (self-loop edges are e >= E: src=dst=e-E).
// ---------------------------------------------------------------------------
__global__ void edge_denom(const int* __restrict__ src, const int* __restrict__ dst,
                           const float* __restrict__ a_s, const float* __restrict__ a_d,
                           float* __restrict__ denom, int E, int N) {
    int e = blockIdx.x * blockDim.x + threadIdx.x;
    if (e >= E + N) return;
    const int s = (e < E) ? src[e] : (e - E);
    const int d = (e < E) ? dst[e] : (e - E);
    float4 as = *(const float4*)(a_s + (size_t)s * NH);
    float4 ad = *(const float4*)(a_d + (size_t)d * NH);
    atomicAdd(&denom[d * NH + 0], edge_ex(as.x, ad.x));
    atomicAdd(&denom[d * NH + 1], edge_ex(as.y, ad.y));
    atomicAdd(&denom[d * NH + 2], edge_ex(as.z, ad.z));
    atomicAdd(&denom[d * NH + 3], edge_ex(as.w, ad.w));
}

// ---------------------------------------------------------------------------
// Edge pass 2: out[dst,h,c] += ht[src,h,c] * alpha[e,h]
// 32 lanes per edge (lane = channel c), 8 edges per 256-thread block.
// ---------------------------------------------------------------------------
__global__ __launch_bounds__(256) void edge_aggregate(
        const int* __restrict__ src, const int* __restrict__ dst,
        const float* __restrict__ a_s, const float* __restrict__ a_d,
        const float* __restrict__ denom, const float* __restrict__ ht,
        float* __restrict__ out, int E, int N) {
    int e = blockIdx.x * 8 + (threadIdx.x >> 5);
    int lane = threadIdx.x & 31;
    if (e >= E + N) return;
    const int s = (e < E) ? src[e] : (e - E);
    const int d = (e < E) ? dst[e] : (e - E);

    float alpha[NH];
#pragma unroll
    for (int hh = 0; hh < NH; ++hh) {
        float ex = edge_ex(a_s[s * NH + hh], a_d[d * NH + hh]);
        alpha[hh] = ex / denom[d * NH + hh];
    }
    const float* hp = ht + (size_t)s * HC;
    float*       op = out + (size_t)d * HC;
#pragma unroll
    for (int hh = 0; hh < NH; ++hh) {
        float v = hp[hh * CH + lane];
        atomicAdd(&op[hh * CH + lane], v * alpha[hh]);
    }
}

// ---------------------------------------------------------------------------
extern "C" void kernel_launch(void* const* d_in, const int* in_sizes, int n_in,
                              void* d_out, int out_size, void* d_ws, size_t ws_size,
                              hipStream_t stream) {
    const float* h       = (const float*)d_in[0];
    const int*   src     = (const int*)d_in[1];
    const int*   dst     = (const int*)d_in[2];
    const float* W       = (const float*)d_in[3];
    const float* att_src = (const float*)d_in[4];
    const float* att_dst = (const float*)d_in[5];
    const float* bias    = (const float*)d_in[6];
    float*       out     = (float*)d_out;

    const int N = in_sizes[0] / IN_F;   // 50000
    const int E = in_sizes[1];          // 800000

    // Workspace layout (floats): ht[N*128] | a_s[N*4] | a_d[N*4] | denom[N*4]
    float* ht    = (float*)d_ws;
    float* a_s   = ht  + (size_t)N * HC;
    float* a_d   = a_s + (size_t)N * NH;
    float* denom = a_d + (size_t)N * NH;

    // 1) init out with bias, zero denom (must re-zero every call)
    {
        int total = N * HC;
        init_out_denom<<<(total + 255) / 256, 256, 0, stream>>>(out, bias, denom, N);
    }
    // 2) ht = h @ W
    gemm_ht<<<(N + 63) / 64, 256, 0, stream>>>(h, W, ht, N);
    // 3) per-node logits
    node_logits<<<(N * NH + 255) / 256, 256, 0, stream>>>(ht, att_src, att_dst,
                                                          a_s, a_d, N);
    // 4) softmax denominator over incoming edges (+ self loops)
    edge_denom<<<(E + N + 255) / 256, 256, 0, stream>>>(src, dst, a_s, a_d,
                                                        denom, E, N);
    // 5) weighted aggregation
    edge_aggregate<<<(E + N + 7) / 8, 256, 0, stream>>>(src, dst, a_s, a_d,
                                                        denom, ht, out, E, N);
}

// Round 2
// 359.095 us; speedup vs baseline: 1.8808x; 1.8808x over previous
//
#include <hip/hip_runtime.h>
#include <math.h>

// Problem constants (fixed by reference): IN=512, H=4, C=32, H*C=128.
constexpr int IN_F = 512;
constexpr int NH   = 4;
constexpr int CH   = 32;
constexpr int HC   = 128;   // NH*CH
constexpr int SCAN_ELEMS = 1024;   // elements per scan block

// ---------------------------------------------------------------------------
// GEMM: ht[M x 128] = h[M x 512] * W[512 x 128], fp32, LDS-tiled.
// ---------------------------------------------------------------------------
__global__ __launch_bounds__(256) void gemm_ht(const float* __restrict__ A,
                                               const float* __restrict__ B,
                                               float* __restrict__ C, int M) {
    constexpr int BM = 64, BK = 32;
    __shared__ float As[BK][BM + 1];
    __shared__ float Bs[BK][HC];

    const int tid  = threadIdx.x;
    const int brow = blockIdx.x * BM;
    const int ty = tid >> 4;
    const int tx = tid & 15;
    const int m0 = ty * 4;
    const int n0 = tx * 8;

    const int ar = tid >> 2;
    const int ac = (tid & 3) * 8;
    const int br = tid >> 5;
    const int bc = (tid & 31) * 4;

    float acc[4][8] = {};

    for (int k0 = 0; k0 < IN_F; k0 += BK) {
        const int grow = brow + ar;
        float4 a0, a1;
        if (grow < M) {
            const float* ap = A + (size_t)grow * IN_F + k0 + ac;
            a0 = *(const float4*)(ap);
            a1 = *(const float4*)(ap + 4);
        } else {
            a0 = make_float4(0.f, 0.f, 0.f, 0.f);
            a1 = a0;
        }
        float4 bq[4];
#pragma unroll
        for (int p = 0; p < 4; ++p)
            bq[p] = *(const float4*)(B + (size_t)(k0 + br + p * 8) * HC + bc);

        __syncthreads();
        As[ac + 0][ar] = a0.x;  As[ac + 1][ar] = a0.y;
        As[ac + 2][ar] = a0.z;  As[ac + 3][ar] = a0.w;
        As[ac + 4][ar] = a1.x;  As[ac + 5][ar] = a1.y;
        As[ac + 6][ar] = a1.z;  As[ac + 7][ar] = a1.w;
#pragma unroll
        for (int p = 0; p < 4; ++p)
            *(float4*)&Bs[br + p * 8][bc] = bq[p];
        __syncthreads();

#pragma unroll
        for (int kk = 0; kk < BK; ++kk) {
            float av[4], bv[8];
#pragma unroll
            for (int i = 0; i < 4; ++i) av[i] = As[kk][m0 + i];
            float4 b0 = *(const float4*)&Bs[kk][n0];
            float4 b1 = *(const float4*)&Bs[kk][n0 + 4];
            bv[0] = b0.x; bv[1] = b0.y; bv[2] = b0.z; bv[3] = b0.w;
            bv[4] = b1.x; bv[5] = b1.y; bv[6] = b1.z; bv[7] = b1.w;
#pragma unroll
            for (int i = 0; i < 4; ++i)
#pragma unroll
                for (int j = 0; j < 8; ++j)
                    acc[i][j] += av[i] * bv[j];
        }
    }

#pragma unroll
    for (int i = 0; i < 4; ++i) {
        const int row = brow + m0 + i;
        if (row < M) {
            float4 c0 = make_float4(acc[i][0], acc[i][1], acc[i][2], acc[i][3]);
            float4 c1 = make_float4(acc[i][4], acc[i][5], acc[i][6], acc[i][7]);
            *(float4*)(C + (size_t)row * HC + n0)     = c0;
            *(float4*)(C + (size_t)row * HC + n0 + 4) = c1;
        }
    }
}

// ---------------------------------------------------------------------------
// Per-(node,head) attention logits.
// ---------------------------------------------------------------------------
__global__ void node_logits(const float* __restrict__ ht,
                            const float* __restrict__ att_src,
                            const float* __restrict__ att_dst,
                            float* __restrict__ a_s, float* __restrict__ a_d,
                            int N) {
    int t = blockIdx.x * blockDim.x + threadIdx.x;
    if (t >= N * NH) return;
    const int n  = t >> 2;
    const int hh = t & 3;
    const float* p  = ht + (size_t)n * HC + hh * CH;
    const float* ps = att_src + hh * CH;
    const float* pd = att_dst + hh * CH;
    float s = 0.f, d = 0.f;
#pragma unroll
    for (int c = 0; c < CH; c += 4) {
        float4 v  = *(const float4*)(p + c);
        float4 as = *(const float4*)(ps + c);
        float4 ad = *(const float4*)(pd + c);
        s += v.x * as.x + v.y * as.y + v.z * as.z + v.w * as.w;
        d += v.x * ad.x + v.y * ad.y + v.z * ad.z + v.w * ad.w;
    }
    a_s[t] = s;
    a_d[t] = d;
}

// ---------------------------------------------------------------------------
// CSR build: counts -> exclusive scan -> scatter src indices by dst.
// ---------------------------------------------------------------------------
__global__ void init_counts(int* __restrict__ counts, int N) {
    int i = blockIdx.x * blockDim.x + threadIdx.x;
    if (i < N) counts[i] = 1;   // start at 1: the self loop
}

__global__ void hist_edges(const int* __restrict__ dst, int* __restrict__ counts, int E) {
    int e = blockIdx.x * blockDim.x + threadIdx.x;
    if (e < E) atomicAdd(&counts[dst[e]], 1);
}

__global__ __launch_bounds__(256) void scan1(const int* __restrict__ counts,
                                             int* __restrict__ row_start,
                                             int* __restrict__ blk_sums, int N) {
    __shared__ int sh[256];
    const int b = blockIdx.x, t = threadIdx.x;
    const int base = b * SCAN_ELEMS + t * 4;
    int v[4], s = 0;
#pragma unroll
    for (int i = 0; i < 4; ++i) {
        v[i] = (base + i < N) ? counts[base + i] : 0;
        s += v[i];
    }
    sh[t] = s;
    __syncthreads();
    for (int off = 1; off < 256; off <<= 1) {
        int x = (t >= off) ? sh[t - off] : 0;
        __syncthreads();
        sh[t] += x;
        __syncthreads();
    }
    int run = sh[t] - s;   // exclusive prefix of this thread within block
#pragma unroll
    for (int i = 0; i < 4; ++i) {
        if (base + i < N) row_start[base + i] = run;
        run += v[i];
    }
    if (t == 255) blk_sums[b] = sh[255];
}

__global__ void scan2(int* __restrict__ blk_sums, int nb) {
    if (threadIdx.x == 0 && blockIdx.x == 0) {
        int acc = 0;
        for (int i = 0; i < nb; ++i) { int v = blk_sums[i]; blk_sums[i] = acc; acc += v; }
    }
}

__global__ void scan3(int* __restrict__ row_start, int* __restrict__ cursor,
                      const int* __restrict__ blk_sums, int N, int total) {
    int i = blockIdx.x * blockDim.x + threadIdx.x;
    if (i < N) {
        int v = row_start[i] + blk_sums[i / SCAN_ELEMS];
        row_start[i] = v;
        cursor[i] = v;
    }
    if (i == 0) row_start[N] = total;
}

__global__ void scatter_edges(const int* __restrict__ src, const int* __restrict__ dst,
                              int* __restrict__ cursor, int* __restrict__ esrc,
                              int E, int N) {
    int e = blockIdx.x * blockDim.x + threadIdx.x;
    if (e >= E + N) return;
    const int s = (e < E) ? src[e] : (e - E);
    const int d = (e < E) ? dst[e] : (e - E);
    int pos = atomicAdd(&cursor[d], 1);
    esrc[pos] = s;
}

// ---------------------------------------------------------------------------
// Fused softmax-denominator + weighted aggregation, one wave per dst node.
// out[d] = (sum_e ex_e * ht[src_e]) / (sum_e ex_e) + bias
// Lane l handles channels 2l, 2l+1 -> head = l>>4.
// ---------------------------------------------------------------------------
__global__ __launch_bounds__(256) void aggregate_csr(
        const int* __restrict__ row_start, const int* __restrict__ esrc,
        const float* __restrict__ a_s, const float* __restrict__ a_d,
        const float* __restrict__ ht, const float* __restrict__ bias,
        float* __restrict__ out, int N) {
    const int n = blockIdx.x * 4 + (threadIdx.x >> 6);
    if (n >= N) return;
    const int lane = threadIdx.x & 63;
    const int hh   = lane >> 4;
    const int c2   = lane * 2;

    const float ad = a_d[n * NH + hh];
    const int rs = row_start[n], re = row_start[n + 1];

    float accx = 0.f, accy = 0.f, exs = 0.f;
    for (int j = rs; j < re; ++j) {
        const int s = esrc[j];
        const float x  = a_s[s * NH + hh] + ad;
        const float ex = __expf(1.0f / (1.0f + __expf(-x)));
        const float2 v = *(const float2*)(ht + (size_t)s * HC + c2);
        accx += ex * v.x;
        accy += ex * v.y;
        exs  += ex;
    }
    const float inv = 1.0f / exs;
    float* op = out + (size_t)n * HC + c2;
    op[0] = accx * inv + bias[c2];
    op[1] = accy * inv + bias[c2 + 1];
}

// ---------------------------------------------------------------------------
extern "C" void kernel_launch(void* const* d_in, const int* in_sizes, int n_in,
                              void* d_out, int out_size, void* d_ws, size_t ws_size,
                              hipStream_t stream) {
    const float* h       = (const float*)d_in[0];
    const int*   src     = (const int*)d_in[1];
    const int*   dst     = (const int*)d_in[2];
    const float* W       = (const float*)d_in[3];
    const float* att_src = (const float*)d_in[4];
    const float* att_dst = (const float*)d_in[5];
    const float* bias    = (const float*)d_in[6];
    float*       out     = (float*)d_out;

    const int N = in_sizes[0] / IN_F;   // 50000
    const int E = in_sizes[1];          // 800000
    const int TOT = E + N;              // edges incl. self loops

    // Workspace layout:
    // ht[N*128] f32 | a_s[N*4] | a_d[N*4] | counts/cursor[N] i32 |
    // row_start[N+1] i32 | blk_sums[64] i32 | esrc[E+N] i32
    float* ht    = (float*)d_ws;
    float* a_s   = ht  + (size_t)N * HC;
    float* a_d   = a_s + (size_t)N * NH;
    int*   cnt   = (int*)(a_d + (size_t)N * NH);   // counts, then cursor
    int*   row_start = cnt + N;
    int*   blk_sums  = row_start + (N + 1);
    int*   esrc      = blk_sums + 64;

    const int nb = (N + SCAN_ELEMS - 1) / SCAN_ELEMS;

    // --- CSR build ---
    init_counts<<<(N + 255) / 256, 256, 0, stream>>>(cnt, N);
    hist_edges<<<(E + 255) / 256, 256, 0, stream>>>(dst, cnt, E);
    scan1<<<nb, 256, 0, stream>>>(cnt, row_start, blk_sums, N);
    scan2<<<1, 64, 0, stream>>>(blk_sums, nb);
    scan3<<<(N + 255) / 256, 256, 0, stream>>>(row_start, cnt, blk_sums, N, TOT);
    scatter_edges<<<(TOT + 255) / 256, 256, 0, stream>>>(src, dst, cnt, esrc, E, N);

    // --- node transform + logits ---
    gemm_ht<<<(N + 63) / 64, 256, 0, stream>>>(h, W, ht, N);
    node_logits<<<(N * NH + 255) / 256, 256, 0, stream>>>(ht, att_src, att_dst,
                                                          a_s, a_d, N);

    // --- fused softmax + aggregation ---
    aggregate_csr<<<(N + 3) / 4, 256, 0, stream>>>(row_start, esrc, a_s, a_d,
                                                   ht, bias, out, N);
}

// Round 4
// 325.415 us; speedup vs baseline: 2.0754x; 1.1035x over previous
//
#include <hip/hip_runtime.h>
#include <math.h>

// Problem constants (fixed by reference): IN=512, H=4, C=32, H*C=128.
constexpr int IN_F = 512;
constexpr int NH   = 4;
constexpr int CH   = 32;
constexpr int HC   = 128;   // NH*CH
constexpr int SCAN_ELEMS = 1024;

typedef short  short8 __attribute__((ext_vector_type(8)));
typedef float  f32x4  __attribute__((ext_vector_type(4)));

__device__ __forceinline__ unsigned short f2bf(float f) {
    unsigned u = __float_as_uint(f);
    unsigned r = (u + 0x7fff + ((u >> 16) & 1)) >> 16;   // RNE
    return (unsigned short)r;
}
__device__ __forceinline__ float bf2f(unsigned short b) {
    return __uint_as_float(((unsigned)b) << 16);
}

// ---------------------------------------------------------------------------
// Pre-kernel: W[512x128] fp32 -> Wt_hi/Wt_lo[128x512] bf16 (transposed split).
// ---------------------------------------------------------------------------
__global__ void prep_w(const float* __restrict__ W,
                       unsigned short* __restrict__ WtHi,
                       unsigned short* __restrict__ WtLo) {
    int t = blockIdx.x * blockDim.x + threadIdx.x;
    if (t >= IN_F * HC) return;
    int k = t >> 7, n = t & 127;
    float f = W[t];
    unsigned short hi = f2bf(f);
    unsigned short lo = f2bf(f - bf2f(hi));
    WtHi[(size_t)n * IN_F + k] = hi;
    WtLo[(size_t)n * IN_F + k] = lo;
}

// ---------------------------------------------------------------------------
// MFMA GEMM: ht[M x 128] = h[M x 512] @ W[512 x 128] via 3-term bf16 split.
// BM=64 rows/block, 256 threads = 4 waves, wave tile 32x64.
// LDS tiles [rows][64k] bf16, row stride 128 B, XOR swizzle (row&7)<<4.
// ---------------------------------------------------------------------------
__device__ __forceinline__ short8 frag_read(const char* tile, int row, int kb) {
    const int sw = (row & 7) << 4;
    const int b0 = row * 128 + ((kb)      ^ sw);
    const int b1 = row * 128 + ((kb + 32) ^ sw);
    ushort4 lo = *(const ushort4*)(tile + b0);
    ushort4 hi = *(const ushort4*)(tile + b1);
    short8 f;
    f[0] = (short)lo.x; f[1] = (short)lo.y; f[2] = (short)lo.z; f[3] = (short)lo.w;
    f[4] = (short)hi.x; f[5] = (short)hi.y; f[6] = (short)hi.z; f[7] = (short)hi.w;
    return f;
}

__global__ __launch_bounds__(256) void gemm_mfma(
        const float* __restrict__ A,
        const unsigned short* __restrict__ WtHi,
        const unsigned short* __restrict__ WtLo,
        float* __restrict__ C, int M) {
    // LDS: Ahi[64][64]bf16(8K) Alo(8K) Bhi[128][64]bf16(16K) Blo(16K) = 48 KB
    __shared__ __align__(16) char smem[49152];
    char* Ahi = smem;
    char* Alo = smem + 8192;
    char* Bhi = smem + 16384;
    char* Blo = smem + 32768;

    const int tid  = threadIdx.x;
    const int lane = tid & 63;
    const int wave = tid >> 6;
    const int wr = wave & 1;        // 0..1 -> 32-row half
    const int wc = wave >> 1;       // 0..1 -> 64-col half
    const int brow = blockIdx.x * 64;

    // A staging map: row = tid>>2 (0..63), kq = (tid&3)*16 (16 floats)
    const int s_ar = tid >> 2;
    const int s_ak = (tid & 3) * 16;
    // B staging map: n = tid>>1 (0..127), kseg = (tid&1)*32 (32 bf16)
    const int s_bn = tid >> 1;
    const int s_bk = (tid & 1) * 32;

    const int lr = lane & 15;       // fragment row/col within 16
    const int lg = lane >> 4;       // k-group

    f32x4 acc[2][4];
#pragma unroll
    for (int i = 0; i < 2; ++i)
#pragma unroll
        for (int j = 0; j < 4; ++j)
            acc[i][j] = f32x4{0.f, 0.f, 0.f, 0.f};

    for (int kc = 0; kc < IN_F; kc += 64) {
        // ---- load A chunk (fp32) ----
        float4 av[4];
        const int grow = brow + s_ar;
        if (grow < M) {
            const float* ap = A + (size_t)grow * IN_F + kc + s_ak;
#pragma unroll
            for (int p = 0; p < 4; ++p) av[p] = *(const float4*)(ap + p * 4);
        } else {
#pragma unroll
            for (int p = 0; p < 4; ++p) av[p] = make_float4(0.f, 0.f, 0.f, 0.f);
        }
        // ---- load B chunk (bf16, pre-transposed) ----
        uint4 bh[4], bl[4];
        {
            const unsigned short* bp = WtHi + (size_t)s_bn * IN_F + kc + s_bk;
            const unsigned short* lp = WtLo + (size_t)s_bn * IN_F + kc + s_bk;
#pragma unroll
            for (int p = 0; p < 4; ++p) {
                bh[p] = *(const uint4*)(bp + p * 8);
                bl[p] = *(const uint4*)(lp + p * 8);
            }
        }

        __syncthreads();   // previous compute done before overwrite

        // ---- convert + write A ----
        {
            unsigned short hb[16], lb[16];
#pragma unroll
            for (int p = 0; p < 4; ++p) {
                const float* f = (const float*)&av[p];
#pragma unroll
                for (int q = 0; q < 4; ++q) {
                    float x = f[q];
                    unsigned short h = f2bf(x);
                    hb[p * 4 + q] = h;
                    lb[p * 4 + q] = f2bf(x - bf2f(h));
                }
            }
            const int sw = (s_ar & 7) << 4;
            const int rb = s_ar * 128;
#pragma unroll
            for (int half = 0; half < 2; ++half) {
                uint4 uh, ul;
                unsigned* ph = (unsigned*)&uh;
                unsigned* pl = (unsigned*)&ul;
#pragma unroll
                for (int q = 0; q < 4; ++q) {
                    ph[q] = (unsigned)hb[half * 8 + q * 2] |
                            ((unsigned)hb[half * 8 + q * 2 + 1] << 16);
                    pl[q] = (unsigned)lb[half * 8 + q * 2] |
                            ((unsigned)lb[half * 8 + q * 2 + 1] << 16);
                }
                const int cb = (s_ak * 2 + half * 16) ^ sw;
                *(uint4*)(Ahi + rb + cb) = uh;
                *(uint4*)(Alo + rb + cb) = ul;
            }
        }
        // ---- write B ----
        {
            const int sw = (s_bn & 7) << 4;
            const int rb = s_bn * 128;
#pragma unroll
            for (int p = 0; p < 4; ++p) {
                const int cb = (s_bk * 2 + p * 16) ^ sw;
                *(uint4*)(Bhi + rb + cb) = bh[p];
                *(uint4*)(Blo + rb + cb) = bl[p];
            }
        }

        __syncthreads();

        // ---- compute: 2 k-steps of 32 ----
#pragma unroll
        for (int s = 0; s < 2; ++s) {
            const int kb = s * 64 + 8 * lg;
            short8 ah[2], al[2];
#pragma unroll
            for (int mi = 0; mi < 2; ++mi) {
                const int row = wr * 32 + mi * 16 + lr;
                ah[mi] = frag_read(Ahi, row, kb);
                al[mi] = frag_read(Alo, row, kb);
            }
            short8 bhf[4], blf[4];
#pragma unroll
            for (int ni = 0; ni < 4; ++ni) {
                const int row = wc * 64 + ni * 16 + lr;
                bhf[ni] = frag_read(Bhi, row, kb);
                blf[ni] = frag_read(Blo, row, kb);
            }
#pragma unroll
            for (int mi = 0; mi < 2; ++mi)
#pragma unroll
                for (int ni = 0; ni < 4; ++ni) {
                    acc[mi][ni] = __builtin_amdgcn_mfma_f32_16x16x32_bf16(
                        ah[mi], bhf[ni], acc[mi][ni], 0, 0, 0);
                    acc[mi][ni] = __builtin_amdgcn_mfma_f32_16x16x32_bf16(
                        al[mi], bhf[ni], acc[mi][ni], 0, 0, 0);
                    acc[mi][ni] = __builtin_amdgcn_mfma_f32_16x16x32_bf16(
                        ah[mi], blf[ni], acc[mi][ni], 0, 0, 0);
                }
        }
    }

    // ---- epilogue: C/D layout col=lane&15, row=4*(lane>>4)+reg ----
#pragma unroll
    for (int mi = 0; mi < 2; ++mi) {
        const int r0 = brow + wr * 32 + mi * 16 + 4 * lg;
#pragma unroll
        for (int ni = 0; ni < 4; ++ni) {
            const int c0 = wc * 64 + ni * 16 + lr;
#pragma unroll
            for (int j = 0; j < 4; ++j) {
                const int r = r0 + j;
                if (r < M) C[(size_t)r * HC + c0] = acc[mi][ni][j];
            }
        }
    }
}

// ---------------------------------------------------------------------------
// Per-(node,head) attention logits.
// ---------------------------------------------------------------------------
__global__ void node_logits(const float* __restrict__ ht,
                            const float* __restrict__ att_src,
                            const float* __restrict__ att_dst,
                            float* __restrict__ a_s, float* __restrict__ a_d,
                            int N) {
    int t = blockIdx.x * blockDim.x + threadIdx.x;
    if (t >= N * NH) return;
    const int n  = t >> 2;
    const int hh = t & 3;
    const float* p  = ht + (size_t)n * HC + hh * CH;
    const float* ps = att_src + hh * CH;
    const float* pd = att_dst + hh * CH;
    float s = 0.f, d = 0.f;
#pragma unroll
    for (int c = 0; c < CH; c += 4) {
        float4 v  = *(const float4*)(p + c);
        float4 as = *(const float4*)(ps + c);
        float4 ad = *(const float4*)(pd + c);
        s += v.x * as.x + v.y * as.y + v.z * as.z + v.w * as.w;
        d += v.x * ad.x + v.y * ad.y + v.z * ad.z + v.w * ad.w;
    }
    a_s[t] = s;
    a_d[t] = d;
}

// ---------------------------------------------------------------------------
// CSR build: counts -> exclusive scan -> scatter src indices by dst.
// ---------------------------------------------------------------------------
__global__ void init_counts(int* __restrict__ counts, int N) {
    int i = blockIdx.x * blockDim.x + threadIdx.x;
    if (i < N) counts[i] = 1;   // self loop
}

__global__ void hist_edges(const int* __restrict__ dst, int* __restrict__ counts, int E) {
    int e = blockIdx.x * blockDim.x + threadIdx.x;
    if (e < E) atomicAdd(&counts[dst[e]], 1);
}

__global__ __launch_bounds__(256) void scan1(const int* __restrict__ counts,
                                             int* __restrict__ row_start,
                                             int* __restrict__ blk_sums, int N) {
    __shared__ int sh[256];
    const int b = blockIdx.x, t = threadIdx.x;
    const int base = b * SCAN_ELEMS + t * 4;
    int v[4], s = 0;
#pragma unroll
    for (int i = 0; i < 4; ++i) {
        v[i] = (base + i < N) ? counts[base + i] : 0;
        s += v[i];
    }
    sh[t] = s;
    __syncthreads();
    for (int off = 1; off < 256; off <<= 1) {
        int x = (t >= off) ? sh[t - off] : 0;
        __syncthreads();
        sh[t] += x;
        __syncthreads();
    }
    int run = sh[t] - s;
#pragma unroll
    for (int i = 0; i < 4; ++i) {
        if (base + i < N) row_start[base + i] = run;
        run += v[i];
    }
    if (t == 255) blk_sums[b] = sh[255];
}

__global__ void scan2(int* __restrict__ blk_sums, int nb) {
    if (threadIdx.x == 0 && blockIdx.x == 0) {
        int acc = 0;
        for (int i = 0; i < nb; ++i) { int v = blk_sums[i]; blk_sums[i] = acc; acc += v; }
    }
}

__global__ void scan3(int* __restrict__ row_start, int* __restrict__ cursor,
                      const int* __restrict__ blk_sums, int N, int total) {
    int i = blockIdx.x * blockDim.x + threadIdx.x;
    if (i < N) {
        int v = row_start[i] + blk_sums[i / SCAN_ELEMS];
        row_start[i] = v;
        cursor[i] = v;
    }
    if (i == 0) row_start[N] = total;
}

__global__ void scatter_edges(const int* __restrict__ src, const int* __restrict__ dst,
                              int* __restrict__ cursor, int* __restrict__ esrc,
                              int E, int N) {
    int e = blockIdx.x * blockDim.x + threadIdx.x;
    if (e >= E + N) return;
    const int s = (e < E) ? src[e] : (e - E);
    const int d = (e < E) ? dst[e] : (e - E);
    int pos = atomicAdd(&cursor[d], 1);
    esrc[pos] = s;
}

// ---------------------------------------------------------------------------
// Fused softmax-denominator + weighted aggregation, one wave per dst node.
// ---------------------------------------------------------------------------
__global__ __launch_bounds__(256) void aggregate_csr(
        const int* __restrict__ row_start, const int* __restrict__ esrc,
        const float* __restrict__ a_s, const float* __restrict__ a_d,
        const float* __restrict__ ht, const float* __restrict__ bias,
        float* __restrict__ out, int N) {
    const int n = blockIdx.x * 4 + (threadIdx.x >> 6);
    if (n >= N) return;
    const int lane = threadIdx.x & 63;
    const int hh   = lane >> 4;
    const int c2   = lane * 2;

    const float ad = a_d[n * NH + hh];
    const int rs = row_start[n], re = row_start[n + 1];

    float accx = 0.f, accy = 0.f, exs = 0.f;
    for (int j = rs; j < re; ++j) {
        const int s = esrc[j];
        const float x  = a_s[s * NH + hh] + ad;
        const float ex = __expf(1.0f / (1.0f + __expf(-x)));
        const float2 v = *(const float2*)(ht + (size_t)s * HC + c2);
        accx += ex * v.x;
        accy += ex * v.y;
        exs  += ex;
    }
    const float inv = 1.0f / exs;
    float* op = out + (size_t)n * HC + c2;
    op[0] = accx * inv + bias[c2];
    op[1] = accy * inv + bias[c2 + 1];
}

// ---------------------------------------------------------------------------
extern "C" void kernel_launch(void* const* d_in, const int* in_sizes, int n_in,
                              void* d_out, int out_size, void* d_ws, size_t ws_size,
                              hipStream_t stream) {
    const float* h       = (const float*)d_in[0];
    const int*   src     = (const int*)d_in[1];
    const int*   dst     = (const int*)d_in[2];
    const float* W       = (const float*)d_in[3];
    const float* att_src = (const float*)d_in[4];
    const float* att_dst = (const float*)d_in[5];
    const float* bias    = (const float*)d_in[6];
    float*       out     = (float*)d_out;

    const int N = in_sizes[0] / IN_F;   // 50000
    const int E = in_sizes[1];          // 800000
    const int TOT = E + N;

    // Workspace layout:
    float* ht    = (float*)d_ws;
    float* a_s   = ht  + (size_t)N * HC;
    float* a_d   = a_s + (size_t)N * NH;
    int*   cnt   = (int*)(a_d + (size_t)N * NH);
    int*   row_start = cnt + N;
    int*   blk_sums  = row_start + (N + 1);
    int*   esrc      = blk_sums + 64;
    // 16B-aligned bf16 W arrays after esrc
    size_t off = ((size_t)((char*)(esrc + TOT) - (char*)d_ws) + 15) & ~(size_t)15;
    unsigned short* WtHi = (unsigned short*)((char*)d_ws + off);
    unsigned short* WtLo = WtHi + (size_t)IN_F * HC;

    const int nb = (N + SCAN_ELEMS - 1) / SCAN_ELEMS;

    // --- CSR build ---
    init_counts<<<(N + 255) / 256, 256, 0, stream>>>(cnt, N);
    hist_edges<<<(E + 255) / 256, 256, 0, stream>>>(dst, cnt, E);
    scan1<<<nb, 256, 0, stream>>>(cnt, row_start, blk_sums, N);
    scan2<<<1, 64, 0, stream>>>(blk_sums, nb);
    scan3<<<(N + 255) / 256, 256, 0, stream>>>(row_start, cnt, blk_sums, N, TOT);
    scatter_edges<<<(TOT + 255) / 256, 256, 0, stream>>>(src, dst, cnt, esrc, E, N);

    // --- node transform (MFMA) + logits ---
    prep_w<<<(IN_F * HC + 255) / 256, 256, 0, stream>>>(W, WtHi, WtLo);
    gemm_mfma<<<(N + 63) / 64, 256, 0, stream>>>(h, WtHi, WtLo, ht, N);
    node_logits<<<(N * NH + 255) / 256, 256, 0, stream>>>(ht, att_src, att_dst,
                                                          a_s, a_d, N);

    // --- fused softmax + aggregation ---
    aggregate_csr<<<(N + 3) / 4, 256, 0, stream>>>(row_start, esrc, a_s, a_d,
                                                   ht, bias, out, N);
}

// Round 7
// 246.800 us; speedup vs baseline: 2.7365x; 1.3185x over previous
//
#include <hip/hip_runtime.h>
#include <math.h>

// Problem constants (fixed by reference): IN=512, H=4, C=32, H*C=128.
constexpr int IN_F = 512;
constexpr int NH   = 4;
constexpr int CH   = 32;
constexpr int HC   = 128;   // NH*CH
constexpr int SCAN_ELEMS = 1024;

typedef short  short8 __attribute__((ext_vector_type(8)));
typedef float  f32x4  __attribute__((ext_vector_type(4)));

typedef __attribute__((address_space(3))) void as3_void;
typedef __attribute__((address_space(1))) void as1_void;
#define GLOAD_LDS16(g, l) \
    __builtin_amdgcn_global_load_lds((const as1_void*)(g), (as3_void*)(l), 16, 0, 0)

__device__ __forceinline__ unsigned short f2bf(float f) {
    unsigned u = __float_as_uint(f);
    unsigned r = (u + 0x7fff + ((u >> 16) & 1)) >> 16;   // RNE
    return (unsigned short)r;
}
__device__ __forceinline__ float bf2f(unsigned short b) {
    return __uint_as_float(((unsigned)b) << 16);
}

// ---------------------------------------------------------------------------
// W[512x128] fp32 -> Wt_hi/Wt_lo[128x512] bf16 (transposed split).
// Fast path uses only WtHi; fallback uses both.
// ---------------------------------------------------------------------------
__global__ void prep_w(const float* __restrict__ W,
                       unsigned short* __restrict__ WtHi,
                       unsigned short* __restrict__ WtLo) {
    int t = blockIdx.x * blockDim.x + threadIdx.x;
    if (t >= IN_F * HC) return;
    int k = t >> 7, n = t & 127;
    float f = W[t];
    unsigned short hi = f2bf(f);
    unsigned short lo = f2bf(f - bf2f(hi));
    WtHi[(size_t)n * IN_F + k] = hi;
    WtLo[(size_t)n * IN_F + k] = lo;
}

// ---------------------------------------------------------------------------
// h fp32 [M*512] -> bf16 [Mpad*512], zero-padded rows.
// ---------------------------------------------------------------------------
__global__ void cvt_h(const float* __restrict__ h, unsigned* __restrict__ hb,
                      int n_elems, int n_pad) {
    int i8 = (blockIdx.x * blockDim.x + threadIdx.x) * 8;
    if (i8 >= n_pad) return;
    uint4 o;
    if (i8 < n_elems) {
        float4 v0 = *(const float4*)(h + i8);
        float4 v1 = *(const float4*)(h + i8 + 4);
        o.x = (unsigned)f2bf(v0.x) | ((unsigned)f2bf(v0.y) << 16);
        o.y = (unsigned)f2bf(v0.z) | ((unsigned)f2bf(v0.w) << 16);
        o.z = (unsigned)f2bf(v1.x) | ((unsigned)f2bf(v1.y) << 16);
        o.w = (unsigned)f2bf(v1.z) | ((unsigned)f2bf(v1.w) << 16);
    } else {
        o = make_uint4(0, 0, 0, 0);
    }
    *(uint4*)(hb + i8 / 2) = o;
}

// ---------------------------------------------------------------------------
// Shared fragment reader: LDS tile rows of 128 B (64 bf16), XOR-swizzled
// 16B chunks: byte = row*128 + (b ^ ((row&7)<<4)).
// ---------------------------------------------------------------------------
__device__ __forceinline__ short8 frag_read(const char* tile, int row, int kb) {
    const int sw = (row & 7) << 4;
    const int b0 = row * 128 + ((kb)      ^ sw);
    const int b1 = row * 128 + ((kb + 32) ^ sw);
    ushort4 lo = *(const ushort4*)(tile + b0);
    ushort4 hi = *(const ushort4*)(tile + b1);
    short8 f;
    f[0] = (short)lo.x; f[1] = (short)lo.y; f[2] = (short)lo.z; f[3] = (short)lo.w;
    f[4] = (short)hi.x; f[5] = (short)hi.y; f[6] = (short)hi.z; f[7] = (short)hi.w;
    return f;
}

// ---------------------------------------------------------------------------
// FAST GEMM: ht[M x 128] = hbf[Mpad x 512] @ WtHi^T, pure bf16, m97-style.
// BM=64, BN=128, BK=64. 256 threads = 4 waves (2x2), wave tile 32x64.
// LDS 24 KB: A[64][64]bf16 (8K) + B[128][64]bf16 (16K), linear dest via
// global_load_lds; swizzle achieved by pre-swizzling the GLOBAL source.
// ---------------------------------------------------------------------------
__global__ __launch_bounds__(256) void gemm_bf16(
        const unsigned short* __restrict__ Abf,   // [Mpad][512]
        const unsigned short* __restrict__ Wt,    // [128][512]
        float* __restrict__ C, int M) {
    __shared__ __align__(16) char smem[24576];
    char* As = smem;          // 8 KB
    char* Bs = smem + 8192;   // 16 KB

    const int tid  = threadIdx.x;
    const int lane = tid & 63;
    const int wave = tid >> 6;
    const int wr  = wave & 1;       // row half (32 rows)
    const int wcq = wave >> 1;      // col half (64 cols)
    const int brow = blockIdx.x * 64;
    const int lr = lane & 15;
    const int lg = lane >> 4;

    f32x4 acc[2][4];
#pragma unroll
    for (int i = 0; i < 2; ++i)
#pragma unroll
        for (int j = 0; j < 4; ++j)
            acc[i][j] = f32x4{0.f, 0.f, 0.f, 0.f};

    for (int kc = 0; kc < IN_F; kc += 64) {
        __syncthreads();   // prior compute done before overwrite
        // ---- stage A (2 chunks/thread) ----
#pragma unroll
        for (int p = 0; p < 2; ++p) {
            const int c = tid + 256 * p;
            const int r = c >> 3, j = c & 7;
            const unsigned short* src = Abf + (size_t)(brow + r) * IN_F + kc
                                        + ((j ^ (r & 7)) << 3);
            GLOAD_LDS16(src, As + wave * 1024 + p * 4096);
        }
        // ---- stage B (4 chunks/thread) ----
#pragma unroll
        for (int p = 0; p < 4; ++p) {
            const int c = tid + 256 * p;
            const int n = c >> 3, j = c & 7;
            const unsigned short* src = Wt + (size_t)n * IN_F + kc
                                        + ((j ^ (n & 7)) << 3);
            GLOAD_LDS16(src, Bs + wave * 1024 + p * 4096);
        }
        __syncthreads();   // drains vmcnt (loads landed) before ds_read

        // ---- compute: 2 k-steps of 32 ----
#pragma unroll
        for (int ks = 0; ks < 2; ++ks) {
            const int kb = ks * 64 + 8 * lg;
            short8 af[2];
#pragma unroll
            for (int mi = 0; mi < 2; ++mi)
                af[mi] = frag_read(As, wr * 32 + mi * 16 + lr, kb);
            short8 bf[4];
#pragma unroll
            for (int ni = 0; ni < 4; ++ni)
                bf[ni] = frag_read(Bs, wcq * 64 + ni * 16 + lr, kb);
#pragma unroll
            for (int mi = 0; mi < 2; ++mi)
#pragma unroll
                for (int ni = 0; ni < 4; ++ni)
                    acc[mi][ni] = __builtin_amdgcn_mfma_f32_16x16x32_bf16(
                        af[mi], bf[ni], acc[mi][ni], 0, 0, 0);
        }
    }

    // ---- epilogue: C/D layout col=lane&15, row=4*(lane>>4)+reg ----
#pragma unroll
    for (int mi = 0; mi < 2; ++mi) {
        const int r0 = brow + wr * 32 + mi * 16 + 4 * lg;
#pragma unroll
        for (int ni = 0; ni < 4; ++ni) {
            const int c0 = wcq * 64 + ni * 16 + lr;
#pragma unroll
            for (int j = 0; j < 4; ++j) {
                const int r = r0 + j;
                if (r < M) C[(size_t)r * HC + c0] = acc[mi][ni][j];
            }
        }
    }
}

// ---------------------------------------------------------------------------
// FALLBACK GEMM (proven round-2): 3-term bf16 split, reg-staged LDS.
// ---------------------------------------------------------------------------
__global__ __launch_bounds__(256) void gemm_mfma(
        const float* __restrict__ A,
        const unsigned short* __restrict__ WtHi,
        const unsigned short* __restrict__ WtLo,
        float* __restrict__ C, int M) {
    __shared__ __align__(16) char smem[49152];
    char* Ahi = smem;
    char* Alo = smem + 8192;
    char* Bhi = smem + 16384;
    char* Blo = smem + 32768;

    const int tid  = threadIdx.x;
    const int lane = tid & 63;
    const int wave = tid >> 6;
    const int wr = wave & 1;
    const int wc = wave >> 1;
    const int brow = blockIdx.x * 64;

    const int s_ar = tid >> 2;
    const int s_ak = (tid & 3) * 16;
    const int s_bn = tid >> 1;
    const int s_bk = (tid & 1) * 32;

    const int lr = lane & 15;
    const int lg = lane >> 4;

    f32x4 acc[2][4];
#pragma unroll
    for (int i = 0; i < 2; ++i)
#pragma unroll
        for (int j = 0; j < 4; ++j)
            acc[i][j] = f32x4{0.f, 0.f, 0.f, 0.f};

    for (int kc = 0; kc < IN_F; kc += 64) {
        float4 av[4];
        const int grow = brow + s_ar;
        if (grow < M) {
            const float* ap = A + (size_t)grow * IN_F + kc + s_ak;
#pragma unroll
            for (int p = 0; p < 4; ++p) av[p] = *(const float4*)(ap + p * 4);
        } else {
#pragma unroll
            for (int p = 0; p < 4; ++p) av[p] = make_float4(0.f, 0.f, 0.f, 0.f);
        }
        uint4 bh[4], bl[4];
        {
            const unsigned short* bp = WtHi + (size_t)s_bn * IN_F + kc + s_bk;
            const unsigned short* lp = WtLo + (size_t)s_bn * IN_F + kc + s_bk;
#pragma unroll
            for (int p = 0; p < 4; ++p) {
                bh[p] = *(const uint4*)(bp + p * 8);
                bl[p] = *(const uint4*)(lp + p * 8);
            }
        }

        __syncthreads();

        {
            unsigned short hb[16], lb[16];
#pragma unroll
            for (int p = 0; p < 4; ++p) {
                const float* f = (const float*)&av[p];
#pragma unroll
                for (int q = 0; q < 4; ++q) {
                    float x = f[q];
                    unsigned short hh2 = f2bf(x);
                    hb[p * 4 + q] = hh2;
                    lb[p * 4 + q] = f2bf(x - bf2f(hh2));
                }
            }
            const int sw = (s_ar & 7) << 4;
            const int rb = s_ar * 128;
#pragma unroll
            for (int half = 0; half < 2; ++half) {
                uint4 uh, ul;
                unsigned* ph = (unsigned*)&uh;
                unsigned* pl = (unsigned*)&ul;
#pragma unroll
                for (int q = 0; q < 4; ++q) {
                    ph[q] = (unsigned)hb[half * 8 + q * 2] |
                            ((unsigned)hb[half * 8 + q * 2 + 1] << 16);
                    pl[q] = (unsigned)lb[half * 8 + q * 2] |
                            ((unsigned)lb[half * 8 + q * 2 + 1] << 16);
                }
                const int cb = (s_ak * 2 + half * 16) ^ sw;
                *(uint4*)(Ahi + rb + cb) = uh;
                *(uint4*)(Alo + rb + cb) = ul;
            }
        }
        {
            const int sw = (s_bn & 7) << 4;
            const int rb = s_bn * 128;
#pragma unroll
            for (int p = 0; p < 4; ++p) {
                const int cb = (s_bk * 2 + p * 16) ^ sw;
                *(uint4*)(Bhi + rb + cb) = bh[p];
                *(uint4*)(Blo + rb + cb) = bl[p];
            }
        }

        __syncthreads();

#pragma unroll
        for (int s = 0; s < 2; ++s) {
            const int kb = s * 64 + 8 * lg;
            short8 ah[2], al[2];
#pragma unroll
            for (int mi = 0; mi < 2; ++mi) {
                const int row = wr * 32 + mi * 16 + lr;
                ah[mi] = frag_read(Ahi, row, kb);
                al[mi] = frag_read(Alo, row, kb);
            }
            short8 bhf[4], blf[4];
#pragma unroll
            for (int ni = 0; ni < 4; ++ni) {
                const int row = wc * 64 + ni * 16 + lr;
                bhf[ni] = frag_read(Bhi, row, kb);
                blf[ni] = frag_read(Blo, row, kb);
            }
#pragma unroll
            for (int mi = 0; mi < 2; ++mi)
#pragma unroll
                for (int ni = 0; ni < 4; ++ni) {
                    acc[mi][ni] = __builtin_amdgcn_mfma_f32_16x16x32_bf16(
                        ah[mi], bhf[ni], acc[mi][ni], 0, 0, 0);
                    acc[mi][ni] = __builtin_amdgcn_mfma_f32_16x16x32_bf16(
                        al[mi], bhf[ni], acc[mi][ni], 0, 0, 0);
                    acc[mi][ni] = __builtin_amdgcn_mfma_f32_16x16x32_bf16(
                        ah[mi], blf[ni], acc[mi][ni], 0, 0, 0);
                }
        }
    }

#pragma unroll
    for (int mi = 0; mi < 2; ++mi) {
        const int r0 = brow + wr * 32 + mi * 16 + 4 * lg;
#pragma unroll
        for (int ni = 0; ni < 4; ++ni) {
            const int c0 = wc * 64 + ni * 16 + lr;
#pragma unroll
            for (int j = 0; j < 4; ++j) {
                const int r = r0 + j;
                if (r < M) C[(size_t)r * HC + c0] = acc[mi][ni][j];
            }
        }
    }
}

// ---------------------------------------------------------------------------
// Per-(node,head) attention logits.
// ---------------------------------------------------------------------------
__global__ void node_logits(const float* __restrict__ ht,
                            const float* __restrict__ att_src,
                            const float* __restrict__ att_dst,
                            float* __restrict__ a_s, float* __restrict__ a_d,
                            int N) {
    int t = blockIdx.x * blockDim.x + threadIdx.x;
    if (t >= N * NH) return;
    const int n  = t >> 2;
    const int hh = t & 3;
    const float* p  = ht + (size_t)n * HC + hh * CH;
    const float* ps = att_src + hh * CH;
    const float* pd = att_dst + hh * CH;
    float s = 0.f, d = 0.f;
#pragma unroll
    for (int c = 0; c < CH; c += 4) {
        float4 v  = *(const float4*)(p + c);
        float4 as = *(const float4*)(ps + c);
        float4 ad = *(const float4*)(pd + c);
        s += v.x * as.x + v.y * as.y + v.z * as.z + v.w * as.w;
        d += v.x * ad.x + v.y * ad.y + v.z * ad.z + v.w * ad.w;
    }
    a_s[t] = s;
    a_d[t] = d;
}

// ---------------------------------------------------------------------------
// CSR build.
// ---------------------------------------------------------------------------
__global__ void init_counts(int* __restrict__ counts, int N) {
    int i = blockIdx.x * blockDim.x + threadIdx.x;
    if (i < N) counts[i] = 1;   // self loop
}

__global__ void hist_edges(const int* __restrict__ dst, int* __restrict__ counts, int E) {
    int e = blockIdx.x * blockDim.x + threadIdx.x;
    if (e < E) atomicAdd(&counts[dst[e]], 1);
}

__global__ __launch_bounds__(256) void scan1(const int* __restrict__ counts,
                                             int* __restrict__ row_start,
                                             int* __restrict__ blk_sums, int N) {
    __shared__ int sh[256];
    const int b = blockIdx.x, t = threadIdx.x;
    const int base = b * SCAN_ELEMS + t * 4;
    int v[4], s = 0;
#pragma unroll
    for (int i = 0; i < 4; ++i) {
        v[i] = (base + i < N) ? counts[base + i] : 0;
        s += v[i];
    }
    sh[t] = s;
    __syncthreads();
    for (int off = 1; off < 256; off <<= 1) {
        int x = (t >= off) ? sh[t - off] : 0;
        __syncthreads();
        sh[t] += x;
        __syncthreads();
    }
    int run = sh[t] - s;
#pragma unroll
    for (int i = 0; i < 4; ++i) {
        if (base + i < N) row_start[base + i] = run;
        run += v[i];
    }
    if (t == 255) blk_sums[b] = sh[255];
}

__global__ void scan2(int* __restrict__ blk_sums, int nb) {
    if (threadIdx.x == 0 && blockIdx.x == 0) {
        int acc = 0;
        for (int i = 0; i < nb; ++i) { int v = blk_sums[i]; blk_sums[i] = acc; acc += v; }
    }
}

__global__ void scan3(int* __restrict__ row_start, int* __restrict__ cursor,
                      const int* __restrict__ blk_sums, int N, int total) {
    int i = blockIdx.x * blockDim.x + threadIdx.x;
    if (i < N) {
        int v = row_start[i] + blk_sums[i / SCAN_ELEMS];
        row_start[i] = v;
        cursor[i] = v;
    }
    if (i == 0) row_start[N] = total;
}

__global__ void scatter_edges(const int* __restrict__ src, const int* __restrict__ dst,
                              int* __restrict__ cursor, int* __restrict__ esrc,
                              int E, int N) {
    int e = blockIdx.x * blockDim.x + threadIdx.x;
    if (e >= E + N) return;
    const int s = (e < E) ? src[e] : (e - E);
    const int d = (e < E) ? dst[e] : (e - E);
    int pos = atomicAdd(&cursor[d], 1);
    esrc[pos] = s;
}

// ---------------------------------------------------------------------------
// Fused softmax + aggregation, one wave per dst node, 2-edge unroll for ILP.
// ---------------------------------------------------------------------------
__global__ __launch_bounds__(256) void aggregate_csr(
        const int* __restrict__ row_start, const int* __restrict__ esrc,
        const float* __restrict__ a_s, const float* __restrict__ a_d,
        const float* __restrict__ ht, const float* __restrict__ bias,
        float* __restrict__ out, int N) {
    const int n = blockIdx.x * 4 + (threadIdx.x >> 6);
    if (n >= N) return;
    const int lane = threadIdx.x & 63;
    const int hh   = lane >> 4;
    const int c2   = lane * 2;

    const float ad = a_d[n * NH + hh];
    const int rs = row_start[n], re = row_start[n + 1];

    float ax0 = 0.f, ay0 = 0.f, es0 = 0.f;
    float ax1 = 0.f, ay1 = 0.f, es1 = 0.f;
    int j = rs;
    for (; j + 1 < re; j += 2) {
        const int s0 = esrc[j], s1 = esrc[j + 1];
        const float x0 = a_s[s0 * NH + hh] + ad;
        const float x1 = a_s[s1 * NH + hh] + ad;
        const float e0 = __expf(1.0f / (1.0f + __expf(-x0)));
        const float e1 = __expf(1.0f / (1.0f + __expf(-x1)));
        const float2 v0 = *(const float2*)(ht + (size_t)s0 * HC + c2);
        const float2 v1 = *(const float2*)(ht + (size_t)s1 * HC + c2);
        ax0 += e0 * v0.x;  ay0 += e0 * v0.y;  es0 += e0;
        ax1 += e1 * v1.x;  ay1 += e1 * v1.y;  es1 += e1;
    }
    if (j < re) {
        const int s0 = esrc[j];
        const float x0 = a_s[s0 * NH + hh] + ad;
        const float e0 = __expf(1.0f / (1.0f + __expf(-x0)));
        const float2 v0 = *(const float2*)(ht + (size_t)s0 * HC + c2);
        ax0 += e0 * v0.x;  ay0 += e0 * v0.y;  es0 += e0;
    }
    const float inv = 1.0f / (es0 + es1);
    float* op = out + (size_t)n * HC + c2;
    op[0] = (ax0 + ax1) * inv + bias[c2];
    op[1] = (ay0 + ay1) * inv + bias[c2 + 1];
}

// ---------------------------------------------------------------------------
extern "C" void kernel_launch(void* const* d_in, const int* in_sizes, int n_in,
                              void* d_out, int out_size, void* d_ws, size_t ws_size,
                              hipStream_t stream) {
    const float* h       = (const float*)d_in[0];
    const int*   src     = (const int*)d_in[1];
    const int*   dst     = (const int*)d_in[2];
    const float* W       = (const float*)d_in[3];
    const float* att_src = (const float*)d_in[4];
    const float* att_dst = (const float*)d_in[5];
    const float* bias    = (const float*)d_in[6];
    float*       out     = (float*)d_out;

    const int N = in_sizes[0] / IN_F;   // 50000
    const int E = in_sizes[1];          // 800000
    const int TOT = E + N;
    const int Mpad = (N + 63) & ~63;

    // Workspace layout:
    float* ht    = (float*)d_ws;
    float* a_s   = ht  + (size_t)N * HC;
    float* a_d   = a_s + (size_t)N * NH;
    int*   cnt   = (int*)(a_d + (size_t)N * NH);
    int*   row_start = cnt + N;
    int*   blk_sums  = row_start + (N + 1);
    int*   esrc      = blk_sums + 64;
    size_t off = ((size_t)((char*)(esrc + TOT) - (char*)d_ws) + 15) & ~(size_t)15;
    unsigned short* WtHi = (unsigned short*)((char*)d_ws + off);
    unsigned short* WtLo = WtHi + (size_t)IN_F * HC;
    unsigned short* hbf  = WtLo + (size_t)IN_F * HC;   // [Mpad][512] bf16
    const size_t need = (size_t)((char*)(hbf + (size_t)Mpad * IN_F) - (char*)d_ws);
    const bool fast = (ws_size >= need);

    const int nb = (N + SCAN_ELEMS - 1) / SCAN_ELEMS;

    // --- CSR build ---
    init_counts<<<(N + 255) / 256, 256, 0, stream>>>(cnt, N);
    hist_edges<<<(E + 255) / 256, 256, 0, stream>>>(dst, cnt, E);
    scan1<<<nb, 256, 0, stream>>>(cnt, row_start, blk_sums, N);
    scan2<<<1, 64, 0, stream>>>(blk_sums, nb);
    scan3<<<(N + 255) / 256, 256, 0, stream>>>(row_start, cnt, blk_sums, N, TOT);
    scatter_edges<<<(TOT + 255) / 256, 256, 0, stream>>>(src, dst, cnt, esrc, E, N);

    // --- node transform (MFMA) ---
    prep_w<<<(IN_F * HC + 255) / 256, 256, 0, stream>>>(W, WtHi, WtLo);
    if (fast) {
        const int n_elems = N * IN_F;
        const int n_pad   = Mpad * IN_F;
        cvt_h<<<(n_pad / 8 + 255) / 256, 256, 0, stream>>>(h, (unsigned*)hbf,
                                                           n_elems, n_pad);
        gemm_bf16<<<Mpad / 64, 256, 0, stream>>>(hbf, WtHi, ht, N);
    } else {
        gemm_mfma<<<(N + 63) / 64, 256, 0, stream>>>(h, WtHi, WtLo, ht, N);
    }
    node_logits<<<(N * NH + 255) / 256, 256, 0, stream>>>(ht, att_src, att_dst,
                                                          a_s, a_d, N);

    // --- fused softmax + aggregation ---
    aggregate_csr<<<(N + 3) / 4, 256, 0, stream>>>(row_start, esrc, a_s, a_d,
                                                   ht, bias, out, N);
}

// Round 8
// 224.762 us; speedup vs baseline: 3.0049x; 1.0981x over previous
//
#include <hip/hip_runtime.h>
#include <math.h>

// Problem constants (fixed by reference): IN=512, H=4, C=32, H*C=128.
constexpr int IN_F = 512;
constexpr int NH   = 4;
constexpr int CH   = 32;
constexpr int HC   = 128;   // NH*CH
constexpr int SCAN_ELEMS = 1024;

typedef short  short8 __attribute__((ext_vector_type(8)));
typedef float  f32x4  __attribute__((ext_vector_type(4)));

typedef __attribute__((address_space(3))) void as3_void;
typedef __attribute__((address_space(1))) void as1_void;
#define GLOAD_LDS16(g, l) \
    __builtin_amdgcn_global_load_lds((const as1_void*)(g), (as3_void*)(l), 16, 0, 0)

__device__ __forceinline__ unsigned short f2bf(float f) {
    unsigned u = __float_as_uint(f);
    unsigned r = (u + 0x7fff + ((u >> 16) & 1)) >> 16;   // RNE
    return (unsigned short)r;
}
__device__ __forceinline__ float bf2f(unsigned short b) {
    return __uint_as_float(((unsigned)b) << 16);
}
// unpack packed bf16x2 (u32) -> two floats
__device__ __forceinline__ float bfu_lo(unsigned u) {
    return __uint_as_float(u << 16);
}
__device__ __forceinline__ float bfu_hi(unsigned u) {
    return __uint_as_float(u & 0xffff0000u);
}

// ---------------------------------------------------------------------------
// W[512x128] fp32 -> Wt[128x512] bf16 (transposed).
// ---------------------------------------------------------------------------
__global__ void prep_w(const float* __restrict__ W,
                       unsigned short* __restrict__ Wt) {
    int t = blockIdx.x * blockDim.x + threadIdx.x;
    if (t >= IN_F * HC) return;
    int k = t >> 7, n = t & 127;
    Wt[(size_t)n * IN_F + k] = f2bf(W[t]);
}

// ---------------------------------------------------------------------------
// h fp32 [M*512] -> bf16 [Mpad*512], zero-padded rows.
// ---------------------------------------------------------------------------
__global__ void cvt_h(const float* __restrict__ h, unsigned* __restrict__ hb,
                      int n_elems, int n_pad) {
    int i8 = (blockIdx.x * blockDim.x + threadIdx.x) * 8;
    if (i8 >= n_pad) return;
    uint4 o;
    if (i8 < n_elems) {
        float4 v0 = *(const float4*)(h + i8);
        float4 v1 = *(const float4*)(h + i8 + 4);
        o.x = (unsigned)f2bf(v0.x) | ((unsigned)f2bf(v0.y) << 16);
        o.y = (unsigned)f2bf(v0.z) | ((unsigned)f2bf(v0.w) << 16);
        o.z = (unsigned)f2bf(v1.x) | ((unsigned)f2bf(v1.y) << 16);
        o.w = (unsigned)f2bf(v1.z) | ((unsigned)f2bf(v1.w) << 16);
    } else {
        o = make_uint4(0, 0, 0, 0);
    }
    *(uint4*)(hb + i8 / 2) = o;
}

// ---------------------------------------------------------------------------
// LDS fragment reader: rows of 128 B (64 bf16), XOR-swizzled 16B chunks:
// byte = row*128 + (b ^ ((row&7)<<4)).
// ---------------------------------------------------------------------------
__device__ __forceinline__ short8 frag_read(const char* tile, int row, int kb) {
    const int sw = (row & 7) << 4;
    const int b0 = row * 128 + ((kb)      ^ sw);
    const int b1 = row * 128 + ((kb + 32) ^ sw);
    ushort4 lo = *(const ushort4*)(tile + b0);
    ushort4 hi = *(const ushort4*)(tile + b1);
    short8 f;
    f[0] = (short)lo.x; f[1] = (short)lo.y; f[2] = (short)lo.z; f[3] = (short)lo.w;
    f[4] = (short)hi.x; f[5] = (short)hi.y; f[6] = (short)hi.z; f[7] = (short)hi.w;
    return f;
}

// ---------------------------------------------------------------------------
// GEMM: htb[M x 128] (bf16) = hbf[Mpad x 512] @ Wt^T, m97-style staging.
// BM=64, BN=128, BK=64. 256 threads = 4 waves (2x2), wave tile 32x64.
// ---------------------------------------------------------------------------
__global__ __launch_bounds__(256) void gemm_bf16(
        const unsigned short* __restrict__ Abf,   // [Mpad][512]
        const unsigned short* __restrict__ Wt,    // [128][512]
        unsigned short* __restrict__ C16, int M) {
    __shared__ __align__(16) char smem[24576];
    char* As = smem;          // 8 KB
    char* Bs = smem + 8192;   // 16 KB

    const int tid  = threadIdx.x;
    const int lane = tid & 63;
    const int wave = tid >> 6;
    const int wr  = wave & 1;       // row half (32 rows)
    const int wcq = wave >> 1;      // col half (64 cols)
    const int brow = blockIdx.x * 64;
    const int lr = lane & 15;
    const int lg = lane >> 4;

    f32x4 acc[2][4];
#pragma unroll
    for (int i = 0; i < 2; ++i)
#pragma unroll
        for (int j = 0; j < 4; ++j)
            acc[i][j] = f32x4{0.f, 0.f, 0.f, 0.f};

    for (int kc = 0; kc < IN_F; kc += 64) {
        __syncthreads();   // prior compute done before overwrite
        // ---- stage A (2 chunks/thread), pre-swizzled global source ----
#pragma unroll
        for (int p = 0; p < 2; ++p) {
            const int c = tid + 256 * p;
            const int r = c >> 3, j = c & 7;
            const unsigned short* src = Abf + (size_t)(brow + r) * IN_F + kc
                                        + ((j ^ (r & 7)) << 3);
            GLOAD_LDS16(src, As + wave * 1024 + p * 4096);
        }
        // ---- stage B (4 chunks/thread) ----
#pragma unroll
        for (int p = 0; p < 4; ++p) {
            const int c = tid + 256 * p;
            const int n = c >> 3, j = c & 7;
            const unsigned short* src = Wt + (size_t)n * IN_F + kc
                                        + ((j ^ (n & 7)) << 3);
            GLOAD_LDS16(src, Bs + wave * 1024 + p * 4096);
        }
        __syncthreads();   // drains vmcnt before ds_read

        // ---- compute: 2 k-steps of 32 ----
#pragma unroll
        for (int ks = 0; ks < 2; ++ks) {
            const int kb = ks * 64 + 8 * lg;
            short8 af[2];
#pragma unroll
            for (int mi = 0; mi < 2; ++mi)
                af[mi] = frag_read(As, wr * 32 + mi * 16 + lr, kb);
            short8 bf[4];
#pragma unroll
            for (int ni = 0; ni < 4; ++ni)
                bf[ni] = frag_read(Bs, wcq * 64 + ni * 16 + lr, kb);
#pragma unroll
            for (int mi = 0; mi < 2; ++mi)
#pragma unroll
                for (int ni = 0; ni < 4; ++ni)
                    acc[mi][ni] = __builtin_amdgcn_mfma_f32_16x16x32_bf16(
                        af[mi], bf[ni], acc[mi][ni], 0, 0, 0);
        }
    }

    // ---- epilogue: bf16 store; C/D layout col=lane&15, row=4*(lane>>4)+reg
#pragma unroll
    for (int mi = 0; mi < 2; ++mi) {
        const int r0 = brow + wr * 32 + mi * 16 + 4 * lg;
#pragma unroll
        for (int ni = 0; ni < 4; ++ni) {
            const int c0 = wcq * 64 + ni * 16 + lr;
#pragma unroll
            for (int j = 0; j < 4; ++j) {
                const int r = r0 + j;
                if (r < M) C16[(size_t)r * HC + c0] = f2bf(acc[mi][ni][j]);
            }
        }
    }
}

// ---------------------------------------------------------------------------
// Per-(node,head) attention logits from bf16 ht.
// ---------------------------------------------------------------------------
__global__ void node_logits(const unsigned* __restrict__ htb32,
                            const float* __restrict__ att_src,
                            const float* __restrict__ att_dst,
                            float* __restrict__ a_s, float* __restrict__ a_d,
                            int N) {
    int t = blockIdx.x * blockDim.x + threadIdx.x;
    if (t >= N * NH) return;
    const int n  = t >> 2;
    const int hh = t & 3;
    const unsigned* p = htb32 + (size_t)n * (HC / 2) + hh * (CH / 2);
    const float* ps = att_src + hh * CH;
    const float* pd = att_dst + hh * CH;
    float s = 0.f, d = 0.f;
#pragma unroll
    for (int i = 0; i < CH / 2; i += 2) {
        uint2 u = *(const uint2*)(p + i);
        float4 as = *(const float4*)(ps + 2 * i);
        float4 ad = *(const float4*)(pd + 2 * i);
        float v0 = bfu_lo(u.x), v1 = bfu_hi(u.x);
        float v2 = bfu_lo(u.y), v3 = bfu_hi(u.y);
        s += v0 * as.x + v1 * as.y + v2 * as.z + v3 * as.w;
        d += v0 * ad.x + v1 * ad.y + v2 * ad.z + v3 * ad.w;
    }
    a_s[t] = s;
    a_d[t] = d;
}

// ---------------------------------------------------------------------------
// CSR build.
// ---------------------------------------------------------------------------
__global__ void init_counts(int* __restrict__ counts, int N) {
    int i = blockIdx.x * blockDim.x + threadIdx.x;
    if (i < N) counts[i] = 1;   // self loop
}

__global__ void hist_edges(const int* __restrict__ dst, int* __restrict__ counts, int E) {
    int e = blockIdx.x * blockDim.x + threadIdx.x;
    if (e < E) atomicAdd(&counts[dst[e]], 1);
}

__global__ __launch_bounds__(256) void scan1(const int* __restrict__ counts,
                                             int* __restrict__ row_start,
                                             int* __restrict__ blk_sums, int N) {
    __shared__ int sh[256];
    const int b = blockIdx.x, t = threadIdx.x;
    const int base = b * SCAN_ELEMS + t * 4;
    int v[4], s = 0;
#pragma unroll
    for (int i = 0; i < 4; ++i) {
        v[i] = (base + i < N) ? counts[base + i] : 0;
        s += v[i];
    }
    sh[t] = s;
    __syncthreads();
    for (int off = 1; off < 256; off <<= 1) {
        int x = (t >= off) ? sh[t - off] : 0;
        __syncthreads();
        sh[t] += x;
        __syncthreads();
    }
    int run = sh[t] - s;
#pragma unroll
    for (int i = 0; i < 4; ++i) {
        if (base + i < N) row_start[base + i] = run;
        run += v[i];
    }
    if (t == 255) blk_sums[b] = sh[255];
}

__global__ void scan2(int* __restrict__ blk_sums, int nb) {
    if (threadIdx.x == 0 && blockIdx.x == 0) {
        int acc = 0;
        for (int i = 0; i < nb; ++i) { int v = blk_sums[i]; blk_sums[i] = acc; acc += v; }
    }
}

__global__ void scan3(int* __restrict__ row_start, int* __restrict__ cursor,
                      const int* __restrict__ blk_sums, int N, int total) {
    int i = blockIdx.x * blockDim.x + threadIdx.x;
    if (i < N) {
        int v = row_start[i] + blk_sums[i / SCAN_ELEMS];
        row_start[i] = v;
        cursor[i] = v;
    }
    if (i == 0) row_start[N] = total;
}

__global__ void scatter_edges(const int* __restrict__ src, const int* __restrict__ dst,
                              int* __restrict__ cursor, int* __restrict__ esrc,
                              int E, int N) {
    int e = blockIdx.x * blockDim.x + threadIdx.x;
    if (e >= E + N) return;
    const int s = (e < E) ? src[e] : (e - E);
    const int d = (e < E) ? dst[e] : (e - E);
    int pos = atomicAdd(&cursor[d], 1);
    esrc[pos] = s;
}

// ---------------------------------------------------------------------------
// Fused softmax + aggregation, one wave per dst node, bf16 ht gather.
// Lane l: u32 = 2 channels (c2 = 2l, 2l+1), head = l>>4.
// ---------------------------------------------------------------------------
__global__ __launch_bounds__(256) void aggregate_csr(
        const int* __restrict__ row_start, const int* __restrict__ esrc,
        const float* __restrict__ a_s, const float* __restrict__ a_d,
        const unsigned* __restrict__ htb32, const float* __restrict__ bias,
        float* __restrict__ out, int N) {
    const int n = blockIdx.x * 4 + (threadIdx.x >> 6);
    if (n >= N) return;
    const int lane = threadIdx.x & 63;
    const int hh   = lane >> 4;
    const int c2   = lane * 2;

    const float ad = a_d[n * NH + hh];
    const int rs = row_start[n], re = row_start[n + 1];

    float ax0 = 0.f, ay0 = 0.f, es0 = 0.f;
    float ax1 = 0.f, ay1 = 0.f, es1 = 0.f;
    int j = rs;
    for (; j + 1 < re; j += 2) {
        const int s0 = esrc[j], s1 = esrc[j + 1];
        const float x0 = a_s[s0 * NH + hh] + ad;
        const float x1 = a_s[s1 * NH + hh] + ad;
        const float e0 = __expf(1.0f / (1.0f + __expf(-x0)));
        const float e1 = __expf(1.0f / (1.0f + __expf(-x1)));
        const unsigned u0 = htb32[(size_t)s0 * (HC / 2) + lane];
        const unsigned u1 = htb32[(size_t)s1 * (HC / 2) + lane];
        ax0 += e0 * bfu_lo(u0);  ay0 += e0 * bfu_hi(u0);  es0 += e0;
        ax1 += e1 * bfu_lo(u1);  ay1 += e1 * bfu_hi(u1);  es1 += e1;
    }
    if (j < re) {
        const int s0 = esrc[j];
        const float x0 = a_s[s0 * NH + hh] + ad;
        const float e0 = __expf(1.0f / (1.0f + __expf(-x0)));
        const unsigned u0 = htb32[(size_t)s0 * (HC / 2) + lane];
        ax0 += e0 * bfu_lo(u0);  ay0 += e0 * bfu_hi(u0);  es0 += e0;
    }
    const float inv = 1.0f / (es0 + es1);
    float* op = out + (size_t)n * HC + c2;
    op[0] = (ax0 + ax1) * inv + bias[c2];
    op[1] = (ay0 + ay1) * inv + bias[c2 + 1];
}

// ---------------------------------------------------------------------------
extern "C" void kernel_launch(void* const* d_in, const int* in_sizes, int n_in,
                              void* d_out, int out_size, void* d_ws, size_t ws_size,
                              hipStream_t stream) {
    const float* h       = (const float*)d_in[0];
    const int*   src     = (const int*)d_in[1];
    const int*   dst     = (const int*)d_in[2];
    const float* W       = (const float*)d_in[3];
    const float* att_src = (const float*)d_in[4];
    const float* att_dst = (const float*)d_in[5];
    const float* bias    = (const float*)d_in[6];
    float*       out     = (float*)d_out;

    const int N = in_sizes[0] / IN_F;   // 50000
    const int E = in_sizes[1];          // 800000
    const int TOT = E + N;
    const int Mpad = (N + 63) & ~63;

    // Workspace layout:
    // htb[N*128] bf16 | a_s[N*4] f32 | a_d[N*4] f32 | cnt[N] | row_start[N+1]
    // | blk_sums[64] | esrc[TOT] | Wt[128*512] bf16 | hbf[Mpad*512] bf16
    unsigned short* htb = (unsigned short*)d_ws;
    float* a_s = (float*)(htb + (size_t)N * HC);
    float* a_d = a_s + (size_t)N * NH;
    int*   cnt = (int*)(a_d + (size_t)N * NH);
    int*   row_start = cnt + N;
    int*   blk_sums  = row_start + (N + 1);
    int*   esrc      = blk_sums + 64;
    size_t off = ((size_t)((char*)(esrc + TOT) - (char*)d_ws) + 15) & ~(size_t)15;
    unsigned short* Wt  = (unsigned short*)((char*)d_ws + off);
    unsigned short* hbf = Wt + (size_t)IN_F * HC;   // [Mpad][512] bf16

    const int nb = (N + SCAN_ELEMS - 1) / SCAN_ELEMS;

    // --- CSR build ---
    init_counts<<<(N + 255) / 256, 256, 0, stream>>>(cnt, N);
    hist_edges<<<(E + 255) / 256, 256, 0, stream>>>(dst, cnt, E);
    scan1<<<nb, 256, 0, stream>>>(cnt, row_start, blk_sums, N);
    scan2<<<1, 64, 0, stream>>>(blk_sums, nb);
    scan3<<<(N + 255) / 256, 256, 0, stream>>>(row_start, cnt, blk_sums, N, TOT);
    scatter_edges<<<(TOT + 255) / 256, 256, 0, stream>>>(src, dst, cnt, esrc, E, N);

    // --- node transform (MFMA, bf16 in/out) ---
    prep_w<<<(IN_F * HC + 255) / 256, 256, 0, stream>>>(W, Wt);
    {
        const int n_elems = N * IN_F;
        const int n_pad   = Mpad * IN_F;
        cvt_h<<<(n_pad / 8 + 255) / 256, 256, 0, stream>>>(h, (unsigned*)hbf,
                                                           n_elems, n_pad);
    }
    gemm_bf16<<<Mpad / 64, 256, 0, stream>>>(hbf, Wt, htb, N);
    node_logits<<<(N * NH + 255) / 256, 256, 0, stream>>>((const unsigned*)htb,
                                                          att_src, att_dst,
                                                          a_s, a_d, N);

    // --- fused softmax + aggregation ---
    aggregate_csr<<<(N + 3) / 4, 256, 0, stream>>>(row_start, esrc, a_s, a_d,
                                                   (const unsigned*)htb, bias,
                                                   out, N);
}